// Round 4
// baseline (460.737 us; speedup 1.0000x reference)
//
#include <hip/hip_runtime.h>
#include <hip/hip_bf16.h>

// LambdaLayer fused forward for MI355X (gfx950).
// B=32 N=4096 C=512 H=4 K=16 U=4 V=128 KS=7
// Pipeline: k0 weights->bf16 W^T | k1 MFMA GEMM qkv=x@W (bf16 out)
//           k2a/k2a2 softmax stats | k2b LN stats | k3/k3b lc | k4 MFMA output.
// R4: fix R3's A-staging swizzle — global source must be LINEAR (as*8), only
//     the ds_write side carries the XOR swizzle; R3 applied it to both, making
//     LDS content identity while frag reads expected swizzle (absmax 40).

#define Bb   32
#define Nn   4096
#define Cc   512
#define Hh   4
#define Kk   16
#define Uu   4
#define Vv   128
#define QKVW 640
#define EPSf 1e-3f

typedef __bf16 bf16;
typedef bf16  bf16x8 __attribute__((ext_vector_type(8)));
typedef bf16  bf16x4 __attribute__((ext_vector_type(4)));
typedef float f32x4  __attribute__((ext_vector_type(4)));

// ---- workspace byte offsets (all 256-aligned); total ~175.2 MB ----
#define WT_OFF   0UL          //  640*512*2      = 655360
#define QKV_OFF  655360UL     //  131072*640*2   = 167772160
#define QMU_OFF  168427520UL  //  131072*4
#define QRS_OFF  168951808UL
#define VMU_OFF  169476096UL
#define VRS_OFF  170000384UL
#define KPM_OFF  170524672UL  //  32*8*64*4 = 65536
#define KPS_OFF  170590208UL
#define KMX_OFF  170655744UL  //  2048*4
#define KIV_OFF  170663936UL
#define LCP_OFF  170672128UL  //  32*16*2048*4 = 4194304
#define LC_OFF   174866432UL  //  32*2048*4    = 262144
// end: 175128576

__device__ inline float bf2f(bf16 x) { return (float)x; }

// ---------------- K0: build W^T bf16 (640 x 512) ----------------
__global__ __launch_bounds__(256) void k0_weights(
    const float* __restrict__ wq, const float* __restrict__ wk,
    const float* __restrict__ wv, bf16* __restrict__ wt)
{
    int idx = blockIdx.x * 256 + threadIdx.x;   // over c*640 + j
    if (idx >= Cc * QKVW) return;
    int c = idx / QKVW, j = idx % QKVW;
    float v;
    if (j < 64)       v = wq[c * 64 + j];
    else if (j < 128) v = wk[c * 64 + (j - 64)];
    else              v = wv[c * 512 + (j - 128)];
    wt[(size_t)j * Cc + c] = (bf16)v;
}

// ---------------- K1: GEMM qkv = x @ W, bf16 MFMA ----------------
// 128x128 tile, BK=64, 4 waves of 64x64. LDS: As/Bs 128x64 bf16 (16KB each),
// unpadded; 16B-slot XOR swizzle (slot ^= row&7).
//   A (reg-staged): global LINEAR -> reg (prefetch 1 step) -> cvt -> ds_write
//     at SWIZZLED slot -> frag read at swizzled slot.
//   B (gload_lds): LDS dest linear (HW), global source PRE-SWIZZLED -> frag
//     read at swizzled slot. (Both give LDS[row][s] = global[s ^ (row&7)].)
__global__ __launch_bounds__(256) void k1_gemm(
    const float* __restrict__ x, const bf16* __restrict__ wt,
    bf16* __restrict__ qkv)
{
    // XCD-chunked swizzle: 5120 = 8 * 640; siblings (same A-panel) share an XCD L2.
    int bid = blockIdx.x;
    int swz = (bid & 7) * 640 + (bid >> 3);
    int bm = swz / 5, bn = swz % 5;
    int row0 = bm * 128, col0 = bn * 128;

    int tid  = threadIdx.x;
    int lane = tid & 63, w = tid >> 6;
    int wr = (w >> 1) * 64, wc = (w & 1) * 64;
    int l15 = lane & 15, g = lane >> 4;

    __shared__ __align__(16) bf16 As[128 * 64];   // 16 KB
    __shared__ __align__(16) bf16 Bs[128 * 64];   // 16 KB

    f32x4 acc[4][4];
#pragma unroll
    for (int m = 0; m < 4; ++m)
#pragma unroll
        for (int c = 0; c < 4; ++c) { acc[m][c][0]=0.f; acc[m][c][1]=0.f; acc[m][c][2]=0.f; acc[m][c][3]=0.f; }

    // ---- A staging map: thread -> 4 rows (it*32+ar), one 8-f32 slot each ----
    const int ar  = tid >> 3;                 // 0..31
    const int as  = tid & 7;                  // slot (8 bf16 = 16B granule)
    const int asw = ((as ^ (ar & 7)) * 8);    // LDS slot (swizzled); r&7==ar&7 for all it
    const float* aptr = x + (size_t)(row0 + ar) * Cc + as * 8;  // LINEAR source

    // ---- B gload_lds map: per wave 4 issues of 1KB; lane -> (row, slot) ----
    const int brl = lane >> 3;                // row within 8-row group
    const int bsl = lane & 7;                 // slot

    // prefetch A for kt=0
    f32x4 pA[4][2];
#pragma unroll
    for (int it = 0; it < 4; ++it) {
        const float* src = aptr + (size_t)it * 32 * Cc;
        pA[it][0] = *(const f32x4*)src;
        pA[it][1] = *(const f32x4*)(src + 4);
    }

    for (int kt = 0; kt < 8; ++kt) {
        const int kb = kt * 64;
        __syncthreads();    // previous compute done before overwriting LDS
        // write prefetched A (cvt f32->bf16, swizzled slot)
#pragma unroll
        for (int it = 0; it < 4; ++it) {
            int r = it * 32 + ar;
            bf16x8 pk;
            pk[0]=(bf16)pA[it][0][0]; pk[1]=(bf16)pA[it][0][1];
            pk[2]=(bf16)pA[it][0][2]; pk[3]=(bf16)pA[it][0][3];
            pk[4]=(bf16)pA[it][1][0]; pk[5]=(bf16)pA[it][1][1];
            pk[6]=(bf16)pA[it][1][2]; pk[7]=(bf16)pA[it][1][3];
            *(bf16x8*)&As[r * 64 + asw] = pk;
        }
        // issue B global_load_lds (linear LDS dest, pre-swizzled global source)
#pragma unroll
        for (int i = 0; i < 4; ++i) {
            int grp = w * 4 + i;
            int row = grp * 8 + brl;
            const bf16* src = wt + (size_t)(col0 + row) * Cc + kb + ((bsl ^ (row & 7)) * 8);
            __builtin_amdgcn_global_load_lds((const void*)src,
                                             (void*)((char*)Bs + grp * 1024), 16, 0, 0);
        }
        // issue A prefetch for kt+1 (consumed after next barrier)
        if (kt < 7) {
#pragma unroll
            for (int it = 0; it < 4; ++it) {
                const float* src = aptr + (size_t)it * 32 * Cc + (kb + 64);
                pA[it][0] = *(const f32x4*)src;
                pA[it][1] = *(const f32x4*)(src + 4);
            }
        }
        __syncthreads();    // drains ds_writes + B gload_lds (+ A prefetch)
        // compute: swizzled frag reads + MFMA
#pragma unroll
        for (int kk = 0; kk < 2; ++kk) {
            bf16x8 aF[4], bF[4];
#pragma unroll
            for (int m = 0; m < 4; ++m) {
                int r = wr + 16 * m + l15;
                aF[m] = *(const bf16x8*)&As[r * 64 + (((kk * 4 + g) ^ (r & 7)) * 8)];
            }
#pragma unroll
            for (int c = 0; c < 4; ++c) {
                int r = wc + 16 * c + l15;
                bF[c] = *(const bf16x8*)&Bs[r * 64 + (((kk * 4 + g) ^ (r & 7)) * 8)];
            }
#pragma unroll
            for (int m = 0; m < 4; ++m)
#pragma unroll
                for (int c = 0; c < 4; ++c)
                    acc[m][c] = __builtin_amdgcn_mfma_f32_16x16x32_bf16(aF[m], bF[c], acc[m][c], 0, 0, 0);
        }
    }
    // epilogue: D row=(lane>>4)*4+r, col=lane&15 (m89-verified)
#pragma unroll
    for (int m = 0; m < 4; ++m)
#pragma unroll
        for (int c = 0; c < 4; ++c) {
            int grow = row0 + wr + 16 * m + (lane >> 4) * 4;
            int gcol = col0 + wc + 16 * c + l15;
#pragma unroll
            for (int r = 0; r < 4; ++r)
                qkv[(size_t)(grow + r) * QKVW + gcol] = (bf16)acc[m][c][r];
        }
}

// ------------- K2a: k softmax partial (max, sumexp) over n-splits -------------
__global__ __launch_bounds__(256) void k2a_kpart(
    const bf16* __restrict__ qkv, float* __restrict__ kpm, float* __restrict__ kps)
{
    int ns = blockIdx.x;
    int b  = blockIdx.y;
    int t  = threadIdx.x;
    int c0 = (t & 7) * 8;
    int stripe = t >> 3;
    float m[8], s[8];
#pragma unroll
    for (int j = 0; j < 8; ++j) { m[j] = -1e30f; s[j] = 0.f; }
    for (int i = 0; i < 16; ++i) {
        int n = ns * 512 + stripe + i * 32;
        bf16x8 kv = *(const bf16x8*)(qkv + (size_t)(b * Nn + n) * QKVW + 64 + c0);
#pragma unroll
        for (int j = 0; j < 8; ++j) {
            float f = bf2f(kv[j]);
            float mn = fmaxf(m[j], f);
            s[j] = s[j] * __expf(m[j] - mn) + __expf(f - mn);
            m[j] = mn;
        }
    }
    __shared__ float pm[64 * 32], ps[64 * 32];
#pragma unroll
    for (int j = 0; j < 8; ++j) { pm[(c0 + j) * 32 + stripe] = m[j]; ps[(c0 + j) * 32 + stripe] = s[j]; }
    __syncthreads();
    if (t < 64) {
        float M = -1e30f;
        for (int i = 0; i < 32; ++i) M = fmaxf(M, pm[t * 32 + i]);
        float S = 0.f;
        for (int i = 0; i < 32; ++i) S += ps[t * 32 + i] * __expf(pm[t * 32 + i] - M);
        kpm[(b * 8 + ns) * 64 + t] = M;
        kps[(b * 8 + ns) * 64 + t] = S;
    }
}

__global__ __launch_bounds__(256) void k2a2_kfinal(
    const float* __restrict__ kpm, const float* __restrict__ kps,
    float* __restrict__ kmax, float* __restrict__ kinv)
{
    int idx = blockIdx.x * 256 + threadIdx.x;
    if (idx >= 2048) return;
    int b = idx >> 6, c = idx & 63;
    float M = -1e30f;
#pragma unroll
    for (int ns = 0; ns < 8; ++ns) M = fmaxf(M, kpm[(b * 8 + ns) * 64 + c]);
    float S = 0.f;
#pragma unroll
    for (int ns = 0; ns < 8; ++ns) S += kps[(b * 8 + ns) * 64 + c] * __expf(kpm[(b * 8 + ns) * 64 + c] - M);
    kmax[idx] = M;
    kinv[idx] = 1.0f / S;
}

// ------------- K2b: LN stats per row for q (64) and v (512) -------------
__global__ __launch_bounds__(256) void k2b_lnstats(
    const bf16* __restrict__ qkv, float* __restrict__ qmu, float* __restrict__ qrs,
    float* __restrict__ vmu, float* __restrict__ vrs)
{
    int row = blockIdx.x * 256 + threadIdx.x;
    const bf16* p = qkv + (size_t)row * QKVW;
    float s = 0.f, ss = 0.f;
#pragma unroll
    for (int i = 0; i < 8; ++i) {
        bf16x8 v = *(const bf16x8*)(p + i * 8);
#pragma unroll
        for (int j = 0; j < 8; ++j) { float f = bf2f(v[j]); s += f; ss += f * f; }
    }
    float mu = s * (1.f / 64.f);
    float var = ss * (1.f / 64.f) - mu * mu;
    qmu[row] = mu; qrs[row] = rsqrtf(var + EPSf);
    s = 0.f; ss = 0.f;
#pragma unroll
    for (int i = 0; i < 64; ++i) {
        bf16x8 v = *(const bf16x8*)(p + 128 + i * 8);
#pragma unroll
        for (int j = 0; j < 8; ++j) { float f = bf2f(v[j]); s += f; ss += f * f; }
    }
    mu = s * (1.f / 512.f);
    var = ss * (1.f / 512.f) - mu * mu;
    vmu[row] = mu; vrs[row] = rsqrtf(var + EPSf);
}

// ------------- K3: lc partials = sum_n softmax(k) (x) LN(v) -------------
__global__ __launch_bounds__(256) void k3_lc(
    const bf16* __restrict__ qkv, const float* __restrict__ kmax, const float* __restrict__ kinv,
    const float* __restrict__ vmu, const float* __restrict__ vrs,
    const float* __restrict__ gv, const float* __restrict__ bv,
    float* __restrict__ lcp)
{
    int ns = blockIdx.x;
    int b  = blockIdx.y;
    int t  = threadIdx.x;

    __shared__ __align__(16) float vln[16 * 512];
    __shared__ float smk[16 * 64];
    __shared__ float gvl[512], bvl[512];
    for (int i = t; i < 512; i += 256) { gvl[i] = gv[i]; bvl[i] = bv[i]; }

    int kk = t >> 4, vg = t & 15;
    float acc[8];
#pragma unroll
    for (int j = 0; j < 8; ++j) acc[j] = 0.f;

    for (int ch = 0; ch < 16; ++ch) {
        int nb = ns * 256 + ch * 16;
        __syncthreads();
        {
            int c0  = (t & 63) * 8;
            int nl0 = t >> 6;
#pragma unroll
            for (int i = 0; i < 4; ++i) {
                int nl = nl0 + i * 4;
                int row = b * Nn + nb + nl;
                bf16x8 v8 = *(const bf16x8*)(qkv + (size_t)row * QKVW + 128 + c0);
                float mu = vmu[row], rs = vrs[row];
#pragma unroll
                for (int j = 0; j < 8; ++j)
                    vln[nl * 512 + c0 + j] = (bf2f(v8[j]) - mu) * rs * gvl[c0 + j] + bvl[c0 + j];
            }
        }
        {
            int c0 = (t & 15) * 4;
            int nl = t >> 4;
            int row = b * Nn + nb + nl;
            bf16x4 k4 = *(const bf16x4*)(qkv + (size_t)row * QKVW + 64 + c0);
#pragma unroll
            for (int j = 0; j < 4; ++j)
                smk[nl * 64 + c0 + j] = __expf(bf2f(k4[j]) - kmax[b * 64 + c0 + j]) * kinv[b * 64 + c0 + j];
        }
        __syncthreads();
#pragma unroll 4
        for (int nl = 0; nl < 16; ++nl) {
#pragma unroll
            for (int u = 0; u < 4; ++u) {
                float sm = smk[nl * 64 + u * 16 + kk];
                f32x4 a = *(const f32x4*)&vln[nl * 512 + u * 128 + vg * 8];
                f32x4 c = *(const f32x4*)&vln[nl * 512 + u * 128 + vg * 8 + 4];
                acc[0] += sm * a[0]; acc[1] += sm * a[1]; acc[2] += sm * a[2]; acc[3] += sm * a[3];
                acc[4] += sm * c[0]; acc[5] += sm * c[1]; acc[6] += sm * c[2]; acc[7] += sm * c[3];
            }
        }
    }
    float* dst = lcp + (size_t)(b * 16 + ns) * 2048 + kk * 128 + vg * 8;
#pragma unroll
    for (int j = 0; j < 8; ++j) dst[j] = acc[j];
}

__global__ __launch_bounds__(256) void k3b_lcreduce(
    const float* __restrict__ lcp, float* __restrict__ lc)
{
    int idx = blockIdx.x * 256 + threadIdx.x;
    int b = idx >> 11, cc = idx & 2047;
    float s = 0.f;
#pragma unroll
    for (int ns = 0; ns < 16; ++ns) s += lcp[(size_t)(b * 16 + ns) * 2048 + cc];
    lc[idx] = s;
}

// ------------- K4 (MFMA): out = yc + yp via banded-A matmul -------------
#define TN4    16
#define NPAN4  15
#define PELEM  1056   // bf16 per panel (2112 B = 2048 used + 64 pad)

__global__ __launch_bounds__(256) void k4_out(
    const bf16* __restrict__ qkv, const float* __restrict__ qmu, const float* __restrict__ qrs,
    const float* __restrict__ vmu, const float* __restrict__ vrs,
    const float* __restrict__ gq, const float* __restrict__ bq,
    const float* __restrict__ gv, const float* __restrict__ bv,
    const float* __restrict__ posw, const float* __restrict__ posb,
    const float* __restrict__ lc, float* __restrict__ out)
{
    const int nt = blockIdx.x, b = blockIdx.y, t = threadIdx.x;
    const int n0 = nt * TN4;

    __shared__ __align__(16) bf16 PN[NPAN4 * PELEM]; // 31680 B  (B panels)
    __shared__ __align__(16) bf16 Ax[64 * 104];      // 13312 B  (A, stride 104 bf16 = 208 B)
    __shared__ __align__(16) bf16 PP[4 * 256];       // 2048 B   (pos_w B-panels for r-MFMA)

    // ---- phase Z: zero A and PP ----
    bf16x8 z8;
#pragma unroll
    for (int j = 0; j < 8; ++j) z8[j] = (bf16)0.f;
    for (int i = t; i < 832; i += 256) *(bf16x8*)&Ax[i * 8] = z8;
    if (t < 128) *(bf16x8*)&PP[t * 8] = z8;
    __syncthreads();

    // ---- phase F: fill PP, lc panels, ring panels, A q-part ----
    if (t < 64) {
        int g = t >> 5, du = t & 31;
        if (du < 28) {
            f32x4 a = *(const f32x4*)(posw + du * 16 + g * 8);
            f32x4 c = *(const f32x4*)(posw + du * 16 + g * 8 + 4);
            bf16x8 pk;
            pk[0]=(bf16)a[0]; pk[1]=(bf16)a[1]; pk[2]=(bf16)a[2]; pk[3]=(bf16)a[3];
            pk[4]=(bf16)c[0]; pk[5]=(bf16)c[1]; pk[6]=(bf16)c[2]; pk[7]=(bf16)c[3];
            *(bf16x8*)&PP[g * 256 + du * 8] = pk;
        }
    }
    {
        int p = t >> 7, v = t & 127;
        const float* src = lc + b * 2048 + p * 8 * 128 + v;
        bf16x8 pk;
#pragma unroll
        for (int j = 0; j < 8; ++j) pk[j] = (bf16)src[j * 128];
        *(bf16x8*)&PN[p * PELEM + v * 8] = pk;
        if (t < 128) {
            bf16x8 ones = z8; ones[0] = (bf16)1.0f;
            *(bf16x8*)&PN[2 * PELEM + t * 8] = ones;
            *(bf16x8*)&PN[3 * PELEM + t * 8] = z8;
        }
    }
    for (int it = t; it < 22 * 16; it += 256) {
        int lr = it >> 4, vo = it & 15;
        int n  = n0 - 3 + lr;
        int pbase = (4 + (lr >> 1)) * PELEM + (lr & 1) * 4;
        if ((unsigned)n < (unsigned)Nn) {
            int row = b * Nn + n;
            float mu = vmu[row], rs = vrs[row];
            float f[4][8];
#pragma unroll
            for (int u = 0; u < 4; ++u) {
                bf16x8 v8 = *(const bf16x8*)(qkv + (size_t)row * QKVW + 128 + u * 128 + vo * 8);
                f32x4 g0 = *(const f32x4*)(gv + u * 128 + vo * 8);
                f32x4 g1 = *(const f32x4*)(gv + u * 128 + vo * 8 + 4);
                f32x4 b0 = *(const f32x4*)(bv + u * 128 + vo * 8);
                f32x4 b1 = *(const f32x4*)(bv + u * 128 + vo * 8 + 4);
#pragma unroll
                for (int j = 0; j < 4; ++j) f[u][j]     = (bf2f(v8[j])     - mu) * rs * g0[j] + b0[j];
#pragma unroll
                for (int j = 0; j < 4; ++j) f[u][4 + j] = (bf2f(v8[4 + j]) - mu) * rs * g1[j] + b1[j];
            }
#pragma unroll
            for (int vi = 0; vi < 8; ++vi) {
                bf16x4 pk;
                pk[0]=(bf16)f[0][vi]; pk[1]=(bf16)f[1][vi]; pk[2]=(bf16)f[2][vi]; pk[3]=(bf16)f[3][vi];
                *(bf16x4*)&PN[pbase + (vo * 8 + vi) * 8] = pk;
            }
        } else {
            bf16x4 zz; zz[0]=(bf16)0.f; zz[1]=(bf16)0.f; zz[2]=(bf16)0.f; zz[3]=(bf16)0.f;
#pragma unroll
            for (int vi = 0; vi < 8; ++vi)
                *(bf16x4*)&PN[pbase + (vo * 8 + vi) * 8] = zz;
        }
    }
    if (t < 128) {
        int row = t >> 1, half = t & 1;
        int n = n0 + (row >> 2), h = row & 3;
        int gr = b * Nn + n;
        int c0 = h * 16 + half * 8;
        bf16x8 q8 = *(const bf16x8*)(qkv + (size_t)gr * QKVW + c0);
        float mu = qmu[gr], rs = qrs[gr];
        f32x4 gg0 = *(const f32x4*)(gq + c0), gg1 = *(const f32x4*)(gq + c0 + 4);
        f32x4 bb0 = *(const f32x4*)(bq + c0), bb1 = *(const f32x4*)(bq + c0 + 4);
        f32x4 pb0 = *(const f32x4*)(posb + half * 8), pb1 = *(const f32x4*)(posb + half * 8 + 4);
        float qbp = 0.f;
        bf16x8 pk;
#pragma unroll
        for (int j = 0; j < 4; ++j) {
            float f = (bf2f(q8[j]) - mu) * rs * gg0[j] + bb0[j];
            qbp += f * pb0[j]; pk[j] = (bf16)f;
        }
#pragma unroll
        for (int j = 0; j < 4; ++j) {
            float f = (bf2f(q8[4 + j]) - mu) * rs * gg1[j] + bb1[j];
            qbp += f * pb1[j]; pk[4 + j] = (bf16)f;
        }
        *(bf16x8*)&Ax[row * 104 + half * 8] = pk;
        float qb = qbp + __shfl_xor(qbp, 1);
        if (!half) Ax[row * 104 + 16] = (bf16)qb;
    }
    __syncthreads();

    // ---- per wave: row-tile rt = wave id ----
    const int lane = t & 63, rt = t >> 6;
    const int g = lane >> 4, l15 = lane & 15;
    const int arow = rt * 16 + l15;

    bf16x8 aF0 = *(const bf16x8*)&Ax[arow * 104 + g * 8];
    f32x4 zf; zf[0]=0.f; zf[1]=0.f; zf[2]=0.f; zf[3]=0.f;
#pragma unroll
    for (int ct = 0; ct < 2; ++ct) {
        bf16x8 bp = *(const bf16x8*)&PP[g * 256 + (ct * 16 + l15) * 8];
        f32x4 rf = __builtin_amdgcn_mfma_f32_16x16x32_bf16(aF0, bp, zf, 0, 0, 0);
        int du = ct * 16 + l15;
#pragma unroll
        for (int reg = 0; reg < 4; ++reg) {
            int row = rt * 16 + g * 4 + reg;
            Ax[row * 104 + 32 + g * 4 + du] = (bf16)rf[reg];
        }
    }

    bf16x8 aF1 = *(const bf16x8*)&Ax[arow * 104 + 32 + g * 8];
    bf16x8 aF2 = *(const bf16x8*)&Ax[arow * 104 + 64 + g * 8];
    const int P1 = (4 + rt * 2 + g) * PELEM;
    const int P2 = (4 + rt * 2 + 4) * PELEM;
    f32x4 acc[8];
#pragma unroll
    for (int c = 0; c < 8; ++c) acc[c] = zf;
#pragma unroll
    for (int c = 0; c < 8; ++c) {
        int vb = (c * 16 + l15) * 8;
        bf16x8 b0 = *(const bf16x8*)&PN[g * PELEM + vb];
        bf16x8 b1 = *(const bf16x8*)&PN[P1 + vb];
        bf16x8 b2 = *(const bf16x8*)&PN[P2 + vb];
        acc[c] = __builtin_amdgcn_mfma_f32_16x16x32_bf16(aF0, b0, acc[c], 0, 0, 0);
        acc[c] = __builtin_amdgcn_mfma_f32_16x16x32_bf16(aF1, b1, acc[c], 0, 0, 0);
        acc[c] = __builtin_amdgcn_mfma_f32_16x16x32_bf16(aF2, b2, acc[c], 0, 0, 0);
    }
#pragma unroll
    for (int c = 0; c < 8; ++c) {
#pragma unroll
        for (int reg = 0; reg < 4; ++reg) {
            int row = rt * 16 + g * 4 + reg;
            int n = n0 + (row >> 2), h = row & 3;
            out[((size_t)(b * Nn + n)) * 512 + h * 128 + c * 16 + l15] = acc[c][reg];
        }
    }
}

extern "C" void kernel_launch(void* const* d_in, const int* in_sizes, int n_in,
                              void* d_out, int out_size, void* d_ws, size_t ws_size,
                              hipStream_t stream) {
    const float* x    = (const float*)d_in[0];
    const float* wq   = (const float*)d_in[1];
    const float* wk   = (const float*)d_in[2];
    const float* wv   = (const float*)d_in[3];
    const float* gq   = (const float*)d_in[4];
    const float* bq   = (const float*)d_in[5];
    const float* gv   = (const float*)d_in[6];
    const float* bv   = (const float*)d_in[7];
    const float* posw = (const float*)d_in[8];
    const float* posb = (const float*)d_in[9];
    float* out = (float*)d_out;

    char* ws = (char*)d_ws;
    bf16*  wt   = (bf16*)(ws + WT_OFF);
    bf16*  qkv  = (bf16*)(ws + QKV_OFF);
    float* qmu  = (float*)(ws + QMU_OFF);
    float* qrs  = (float*)(ws + QRS_OFF);
    float* vmu  = (float*)(ws + VMU_OFF);
    float* vrs  = (float*)(ws + VRS_OFF);
    float* kpm  = (float*)(ws + KPM_OFF);
    float* kps  = (float*)(ws + KPS_OFF);
    float* kmax = (float*)(ws + KMX_OFF);
    float* kinv = (float*)(ws + KIV_OFF);
    float* lcp  = (float*)(ws + LCP_OFF);
    float* lc   = (float*)(ws + LC_OFF);

    k0_weights<<<(Cc * QKVW + 255) / 256, 256, 0, stream>>>(wq, wk, wv, wt);
    k1_gemm<<<5120, 256, 0, stream>>>(x, wt, qkv);
    k2a_kpart<<<dim3(8, 32), 256, 0, stream>>>(qkv, kpm, kps);
    k2a2_kfinal<<<8, 256, 0, stream>>>(kpm, kps, kmax, kinv);
    k2b_lnstats<<<512, 256, 0, stream>>>(qkv, qmu, qrs, vmu, vrs);
    k3_lc<<<dim3(16, 32), 256, 0, stream>>>(qkv, kmax, kinv, vmu, vrs, gv, bv, lcp);
    k3b_lcreduce<<<256, 256, 0, stream>>>(lcp, lc);
    k4_out<<<dim3(Nn / TN4, Bb), 256, 0, stream>>>(qkv, qmu, qrs, vmu, vrs, gq, bq, gv, bv,
                                                   posw, posb, lc, out);
}